// Round 1
// baseline (453.561 us; speedup 1.0000x reference)
//
#include <hip/hip_runtime.h>
#include <hip/hip_bf16.h>

// Problem constants (from setup_inputs): N=10000, E=320000, FIN=512, FH=128, FOUT=40
// Derived at launch from in_sizes where cheap.

#define HS (1u << 20)          // hash table slots (load factor ~0.3 at E=320k)
#define HMASK (HS - 1u)
#define EMPTY_KEY 0xFFFFFFFFu

__device__ __forceinline__ unsigned hash_u32(unsigned key) {
    unsigned h = key * 2654435761u;
    h ^= h >> 15;
    return h & HMASK;
}

// ---- deg count (in-degree) + hash insert of edge keys ----
__global__ void k_deg_hash(const int* __restrict__ src, const int* __restrict__ dst,
                           int E, int Nn, float* __restrict__ deg,
                           unsigned* __restrict__ hkeys, unsigned* __restrict__ hcnt) {
    int e = blockIdx.x * blockDim.x + threadIdx.x;
    if (e >= E) return;
    int s = src[e], d = dst[e];
    atomicAdd(&deg[d], 1.0f);
    unsigned key = (unsigned)s * (unsigned)Nn + (unsigned)d;
    unsigned h = hash_u32(key);
    for (;;) {
        unsigned prev = atomicCAS(&hkeys[h], EMPTY_KEY, key);
        if (prev == EMPTY_KEY || prev == key) { atomicAdd(&hcnt[h], 1u); break; }
        h = (h + 1u) & HMASK;
    }
}

__global__ void k_dinv(const float* __restrict__ deg, float* __restrict__ dinv, int Nn) {
    int i = blockIdx.x * blockDim.x + threadIdx.x;
    if (i >= Nn) return;
    dinv[i] = rsqrtf(deg[i] + 1.0f);   // +1 self-loop; always > 0
}

// ---- simple fp32 tiled GEMM: C[M,N] = A[M,K] @ B[K,N]; 64x64 tile, 4x4/thread ----
__global__ void gemm64(const float* __restrict__ A, const float* __restrict__ B,
                       float* __restrict__ C, int M, int N, int K) {
    __shared__ float As[16][64];
    __shared__ float Bs[16][64];
    int row0 = blockIdx.x * 64, col0 = blockIdx.y * 64;
    int t = threadIdx.x;
    int tx = t & 15, ty = t >> 4;
    float acc[4][4] = {};
    for (int k0 = 0; k0 < K; k0 += 16) {
#pragma unroll
        for (int i = 0; i < 4; i++) {
            int idx = t + i * 256;          // 0..1023
            int m = idx >> 4, kk = idx & 15;
            float va = 0.f;
            if (row0 + m < M) va = A[(size_t)(row0 + m) * K + k0 + kk];
            As[kk][m] = va;
            int k2 = idx >> 6, n2 = idx & 63;
            float vb = 0.f;
            if (col0 + n2 < N) vb = B[(size_t)(k0 + k2) * N + col0 + n2];
            Bs[k2][n2] = vb;
        }
        __syncthreads();
#pragma unroll
        for (int kk = 0; kk < 16; kk++) {
            float a[4], b[4];
#pragma unroll
            for (int i = 0; i < 4; i++) a[i] = As[kk][ty * 4 + i];
#pragma unroll
            for (int j = 0; j < 4; j++) b[j] = Bs[kk][tx * 4 + j];
#pragma unroll
            for (int i = 0; i < 4; i++)
#pragma unroll
                for (int j = 0; j < 4; j++) acc[i][j] += a[i] * b[j];
        }
        __syncthreads();
    }
#pragma unroll
    for (int i = 0; i < 4; i++) {
        int m = row0 + ty * 4 + i;
        if (m >= M) continue;
#pragma unroll
        for (int j = 0; j < 4; j++) {
            int n = col0 + tx * 4 + j;
            if (n < N) C[(size_t)m * N + n] = acc[i][j];
        }
    }
}

// ---- edge aggregation: Hout[d] += Hin[s] * dinv[s]*dinv[d], plus self-loops ----
template <int F>
__global__ void k_agg(const int* __restrict__ src, const int* __restrict__ dst,
                      int E, int Nn, const float* __restrict__ dinv,
                      const float* __restrict__ Hin, float* __restrict__ Hout) {
    int idx = blockIdx.x * blockDim.x + threadIdx.x;
    int total = E + Nn;
    int e = idx / F;
    int f = idx - e * F;
    if (e >= total) return;
    int s, d;
    if (e < E) { s = src[e]; d = dst[e]; } else { s = d = e - E; }
    float w = dinv[s] * dinv[d];
    atomicAdd(&Hout[(size_t)d * F + f], Hin[(size_t)s * F + f] * w);
}

__global__ void k_bias_relu(float* __restrict__ H, const float* __restrict__ b,
                            int total, int F) {
    int idx = blockIdx.x * blockDim.x + threadIdx.x;
    if (idx >= total) return;
    float v = H[idx] + b[idx % F];
    H[idx] = v > 0.f ? v : 0.f;
}

// ---- reg = sum over edge instances (s,d) of count(d,s) ----
__global__ void k_reg(const int* __restrict__ src, const int* __restrict__ dst,
                      int E, int Nn, const unsigned* __restrict__ hkeys,
                      const unsigned* __restrict__ hcnt, float* __restrict__ regp) {
    int e = blockIdx.x * blockDim.x + threadIdx.x;
    if (e >= E) return;
    int s = src[e], d = dst[e];
    unsigned key = (unsigned)d * (unsigned)Nn + (unsigned)s;
    unsigned h = hash_u32(key);
    unsigned c = 0;
    for (;;) {
        unsigned k = hkeys[h];
        if (k == EMPTY_KEY) break;
        if (k == key) { c = hcnt[h]; break; }
        h = (h + 1u) & HMASK;
    }
    if (c) atomicAdd(regp, (float)c);
}

// ---- +b2, log_softmax per row (one wave per row), plus final reg write ----
__global__ void k_lsm(const float* __restrict__ agg2, const float* __restrict__ b2,
                      const float* __restrict__ regp, float* __restrict__ out,
                      int Nn, int F) {
    int r = blockIdx.x;
    int f = threadIdx.x;
    float v = -1e30f;
    if (f < F) v = agg2[(size_t)r * F + f] + b2[f];
    float m = v;
#pragma unroll
    for (int off = 32; off; off >>= 1) m = fmaxf(m, __shfl_xor(m, off, 64));
    float ex = (f < F) ? expf(v - m) : 0.f;
    float ssum = ex;
#pragma unroll
    for (int off = 32; off; off >>= 1) ssum += __shfl_xor(ssum, off, 64);
    if (f < F) out[(size_t)r * F + f] = v - m - logf(ssum);
    if (r == 0 && f == 0) out[(size_t)Nn * F] = regp[0];
}

extern "C" void kernel_launch(void* const* d_in, const int* in_sizes, int n_in,
                              void* d_out, int out_size, void* d_ws, size_t ws_size,
                              hipStream_t stream) {
    const float* x  = (const float*)d_in[0];
    const int*   ei = (const int*)d_in[1];
    const float* W1 = (const float*)d_in[2];
    const float* b1 = (const float*)d_in[3];
    const float* W2 = (const float*)d_in[4];
    const float* b2 = (const float*)d_in[5];
    float* out = (float*)d_out;

    const int FH   = in_sizes[3];            // 128
    const int FOUT = in_sizes[5];            // 40
    const int FIN  = in_sizes[2] / FH;       // 512
    const int Nn   = in_sizes[0] / FIN;      // 10000
    const int E    = in_sizes[1] / 2;        // 320000
    const int* src = ei;
    const int* dst = ei + E;

    // ---- workspace layout (float units) ----
    float* ws = (float*)d_ws;
    // zero-init region (contiguous):
    float*    AGG1  = ws;                         // Nn*FH      = 1,280,000
    float*    AGG2  = AGG1 + (size_t)Nn * FH;     // Nn*FOUT    =   400,000
    float*    deg   = AGG2 + (size_t)Nn * FOUT;   // Nn         =    10,000
    float*    regp  = deg + Nn;                   // 1 (+15 pad)
    unsigned* hcnt  = (unsigned*)(regp + 16);     // HS
    size_t zero_bytes = ((size_t)Nn * FH + (size_t)Nn * FOUT + Nn + 16 + HS) * 4;
    // non-init region:
    float*    dinv  = (float*)(hcnt + HS);        // Nn
    float*    H0    = dinv + Nn;                  // Nn*FH
    float*    LG0   = H0 + (size_t)Nn * FH;       // Nn*FOUT
    unsigned* hkeys = (unsigned*)(LG0 + (size_t)Nn * FOUT);  // HS

    hipMemsetAsync(ws, 0, zero_bytes, stream);
    hipMemsetAsync(hkeys, 0xFF, (size_t)HS * 4, stream);

    k_deg_hash<<<(E + 255) / 256, 256, 0, stream>>>(src, dst, E, Nn, deg, hkeys, hcnt);
    k_dinv<<<(Nn + 255) / 256, 256, 0, stream>>>(deg, dinv, Nn);

    // H0 = X @ W1
    gemm64<<<dim3((Nn + 63) / 64, (FH + 63) / 64), 256, 0, stream>>>(x, W1, H0, Nn, FH, FIN);
    // AGG1 = scatter-sum(H0 * norm)
    {
        long long tot = (long long)(E + Nn) * FH;
        k_agg<128><<<(unsigned)((tot + 255) / 256), 256, 0, stream>>>(src, dst, E, Nn, dinv, H0, AGG1);
    }
    // AGG1 = relu(AGG1 + b1)
    k_bias_relu<<<((size_t)Nn * FH + 255) / 256, 256, 0, stream>>>(AGG1, b1, Nn * FH, FH);
    // LG0 = AGG1 @ W2
    gemm64<<<dim3((Nn + 63) / 64, (FOUT + 63) / 64), 256, 0, stream>>>(AGG1, W2, LG0, Nn, FOUT, FH);
    // AGG2 = scatter-sum(LG0 * norm)
    {
        long long tot = (long long)(E + Nn) * FOUT;
        k_agg<40><<<(unsigned)((tot + 255) / 256), 256, 0, stream>>>(src, dst, E, Nn, dinv, LG0, AGG2);
    }
    // reg lookup (must precede k_lsm which reads regp)
    k_reg<<<(E + 255) / 256, 256, 0, stream>>>(src, dst, E, Nn, hkeys, hcnt, regp);
    // log_softmax(AGG2 + b2) -> out[0 .. Nn*FOUT), reg -> out[Nn*FOUT]
    k_lsm<<<Nn, 64, 0, stream>>>(AGG2, b2, regp, out, Nn, FOUT);
}

// Round 2
// 343.391 us; speedup vs baseline: 1.3208x; 1.3208x over previous
//
#include <hip/hip_runtime.h>
#include <hip/hip_bf16.h>

// Problem: N=10000, E=320000, FIN=512, FH=128, FOUT=40 (derived from in_sizes).
// Pipeline: deg+hash -> scan(rowptr,dinv) -> CSR fill -> GEMM1 -> gather-agg1(+bias+relu)
//           -> GEMM2 -> reg lookup -> gather-agg2 + log_softmax (fused).

#define HS (1u << 20)
#define HMASK (HS - 1u)
#define EMPTY_KEY 0xFFFFFFFFu

__device__ __forceinline__ unsigned hash_u32(unsigned key) {
    unsigned h = key * 2654435761u;
    h ^= h >> 15;
    return h & HMASK;
}

// ---- in-degree count + hash insert of edge keys (for reg) ----
__global__ void k_deg_hash(const int* __restrict__ src, const int* __restrict__ dst,
                           int E, int Nn, int* __restrict__ deg,
                           unsigned* __restrict__ hkeys, unsigned* __restrict__ hcnt) {
    int e = blockIdx.x * blockDim.x + threadIdx.x;
    if (e >= E) return;
    int s = src[e], d = dst[e];
    atomicAdd(&deg[d], 1);
    unsigned key = (unsigned)s * (unsigned)Nn + (unsigned)d;
    unsigned h = hash_u32(key);
    for (;;) {
        unsigned prev = atomicCAS(&hkeys[h], EMPTY_KEY, key);
        if (prev == EMPTY_KEY || prev == key) { atomicAdd(&hcnt[h], 1u); break; }
        h = (h + 1u) & HMASK;
    }
}

// ---- single-block exclusive scan of deg -> rowptr; also dinv = rsqrt(deg+1) ----
__global__ void k_scan(const int* __restrict__ deg, int* __restrict__ rowptr,
                       float* __restrict__ dinv, int Nn) {
    __shared__ int part[256];
    int t = threadIdx.x;
    int per = (Nn + 255) / 256;
    int beg = t * per, lim = min(beg + per, Nn);
    int sum = 0;
    for (int i = beg; i < lim; i++) sum += deg[i];
    part[t] = sum;
    __syncthreads();
    for (int off = 1; off < 256; off <<= 1) {
        int v = (t >= off) ? part[t - off] : 0;
        __syncthreads();
        part[t] += v;
        __syncthreads();
    }
    int run = (t > 0) ? part[t - 1] : 0;
    for (int i = beg; i < lim; i++) {
        rowptr[i] = run;
        run += deg[i];
        dinv[i] = rsqrtf((float)deg[i] + 1.0f);  // +1 self-loop
    }
    if (t == 255) rowptr[Nn] = run;
}

// ---- scatter edges into CSR buckets ----
__global__ void k_fill(const int* __restrict__ src, const int* __restrict__ dst, int E,
                       const int* __restrict__ rowptr, int* __restrict__ cursor,
                       int* __restrict__ csr) {
    int e = blockIdx.x * blockDim.x + threadIdx.x;
    if (e >= E) return;
    int d = dst[e];
    int pos = atomicAdd(&cursor[d], 1);
    csr[rowptr[d] + pos] = src[e];
}

// ---- fp32 tiled GEMM: C[M,N] = A[M,K] @ B[K,N]; 64x64 tile, 4x4/thread ----
__global__ void gemm64(const float* __restrict__ A, const float* __restrict__ B,
                       float* __restrict__ C, int M, int N, int K) {
    __shared__ float As[16][64];
    __shared__ float Bs[16][64];
    int row0 = blockIdx.x * 64, col0 = blockIdx.y * 64;
    int t = threadIdx.x;
    int tx = t & 15, ty = t >> 4;
    float acc[4][4] = {};
    for (int k0 = 0; k0 < K; k0 += 16) {
#pragma unroll
        for (int i = 0; i < 4; i++) {
            int idx = t + i * 256;
            int m = idx >> 4, kk = idx & 15;
            float va = 0.f;
            if (row0 + m < M) va = A[(size_t)(row0 + m) * K + k0 + kk];
            As[kk][m] = va;
            int k2 = idx >> 6, n2 = idx & 63;
            float vb = 0.f;
            if (col0 + n2 < N) vb = B[(size_t)(k0 + k2) * N + col0 + n2];
            Bs[k2][n2] = vb;
        }
        __syncthreads();
#pragma unroll
        for (int kk = 0; kk < 16; kk++) {
            float a[4], b[4];
#pragma unroll
            for (int i = 0; i < 4; i++) a[i] = As[kk][ty * 4 + i];
#pragma unroll
            for (int j = 0; j < 4; j++) b[j] = Bs[kk][tx * 4 + j];
#pragma unroll
            for (int i = 0; i < 4; i++)
#pragma unroll
                for (int j = 0; j < 4; j++) acc[i][j] += a[i] * b[j];
        }
        __syncthreads();
    }
#pragma unroll
    for (int i = 0; i < 4; i++) {
        int m = row0 + ty * 4 + i;
        if (m >= M) continue;
#pragma unroll
        for (int j = 0; j < 4; j++) {
            int n = col0 + tx * 4 + j;
            if (n < N) C[(size_t)m * N + n] = acc[i][j];
        }
    }
}

// ---- layer-1 gather aggregation, wave per dst node, FH=128 (float2/lane), fused bias+relu ----
__global__ void k_agg1(const int* __restrict__ rowptr, const int* __restrict__ csr,
                       const float* __restrict__ dinv, const float* __restrict__ H,
                       const float* __restrict__ b1, float* __restrict__ out, int Nn) {
    int wid = (blockIdx.x * blockDim.x + threadIdx.x) >> 6;
    int lane = threadIdx.x & 63;
    if (wid >= Nn) return;
    float dd = dinv[wid];
    const float2* H2 = (const float2*)H;
    float2 h = H2[(size_t)wid * 64 + lane];
    float sw = dd * dd;
    float accx = h.x * sw, accy = h.y * sw;   // self-loop
    int beg = rowptr[wid], end = rowptr[wid + 1];
    int j = beg;
    for (; j + 1 < end; j += 2) {
        int s0 = csr[j], s1 = csr[j + 1];
        float w0 = dinv[s0] * dd, w1 = dinv[s1] * dd;
        float2 a = H2[(size_t)s0 * 64 + lane];
        float2 b = H2[(size_t)s1 * 64 + lane];
        accx += w0 * a.x + w1 * b.x;
        accy += w0 * a.y + w1 * b.y;
    }
    if (j < end) {
        int s0 = csr[j];
        float w0 = dinv[s0] * dd;
        float2 a = H2[(size_t)s0 * 64 + lane];
        accx += w0 * a.x;
        accy += w0 * a.y;
    }
    float2 bb = ((const float2*)b1)[lane];
    float vx = accx + bb.x, vy = accy + bb.y;
    float2 o;
    o.x = vx > 0.f ? vx : 0.f;
    o.y = vy > 0.f ? vy : 0.f;
    ((float2*)out)[(size_t)wid * 64 + lane] = o;
}

// ---- reg = sum over edge instances (s,d) of count(d,s) ----
__global__ void k_reg(const int* __restrict__ src, const int* __restrict__ dst,
                      int E, int Nn, const unsigned* __restrict__ hkeys,
                      const unsigned* __restrict__ hcnt, float* __restrict__ regp) {
    int e = blockIdx.x * blockDim.x + threadIdx.x;
    if (e >= E) return;
    int s = src[e], d = dst[e];
    unsigned key = (unsigned)d * (unsigned)Nn + (unsigned)s;
    unsigned h = hash_u32(key);
    unsigned c = 0;
    for (;;) {
        unsigned k = hkeys[h];
        if (k == EMPTY_KEY) break;
        if (k == key) { c = hcnt[h]; break; }
        h = (h + 1u) & HMASK;
    }
    if (c) atomicAdd(regp, (float)c);
}

// ---- layer-2 gather aggregation + bias + log_softmax, wave per dst node ----
__global__ void k_agg2_lsm(const int* __restrict__ rowptr, const int* __restrict__ csr,
                           const float* __restrict__ dinv, const float* __restrict__ LG,
                           const float* __restrict__ b2, const float* __restrict__ regp,
                           float* __restrict__ out, int Nn, int F) {
    int wid = (blockIdx.x * blockDim.x + threadIdx.x) >> 6;
    int lane = threadIdx.x & 63;
    if (wid >= Nn) return;
    float dd = dinv[wid];
    bool act = lane < F;
    float acc = act ? LG[(size_t)wid * F + lane] * dd * dd : 0.f;  // self-loop
    int beg = rowptr[wid], end = rowptr[wid + 1];
    int j = beg;
    for (; j + 1 < end; j += 2) {
        int s0 = csr[j], s1 = csr[j + 1];
        float w0 = dinv[s0] * dd, w1 = dinv[s1] * dd;
        float a0 = act ? LG[(size_t)s0 * F + lane] : 0.f;
        float a1 = act ? LG[(size_t)s1 * F + lane] : 0.f;
        acc += w0 * a0 + w1 * a1;
    }
    if (j < end) {
        int s0 = csr[j];
        float w0 = dinv[s0] * dd;
        float a0 = act ? LG[(size_t)s0 * F + lane] : 0.f;
        acc += w0 * a0;
    }
    float v = act ? acc + b2[lane] : -1e30f;
    float m = v;
#pragma unroll
    for (int off = 32; off; off >>= 1) m = fmaxf(m, __shfl_xor(m, off, 64));
    float ex = act ? expf(v - m) : 0.f;
    float ssum = ex;
#pragma unroll
    for (int off = 32; off; off >>= 1) ssum += __shfl_xor(ssum, off, 64);
    if (act) out[(size_t)wid * F + lane] = v - m - logf(ssum);
    if (wid == 0 && lane == 0) out[(size_t)Nn * F] = regp[0];
}

extern "C" void kernel_launch(void* const* d_in, const int* in_sizes, int n_in,
                              void* d_out, int out_size, void* d_ws, size_t ws_size,
                              hipStream_t stream) {
    const float* x  = (const float*)d_in[0];
    const int*   ei = (const int*)d_in[1];
    const float* W1 = (const float*)d_in[2];
    const float* b1 = (const float*)d_in[3];
    const float* W2 = (const float*)d_in[4];
    const float* b2 = (const float*)d_in[5];
    float* out = (float*)d_out;

    const int FH   = in_sizes[3];            // 128
    const int FOUT = in_sizes[5];            // 40
    const int FIN  = in_sizes[2] / FH;       // 512
    const int Nn   = in_sizes[0] / FIN;      // 10000
    const int E    = in_sizes[1] / 2;        // 320000
    const int* src = ei;
    const int* dst = ei + E;

    // ---- workspace layout ----
    // zero-init region (contiguous): deg, cursor, regp(+pad), hcnt
    int*      deg    = (int*)d_ws;                    // Nn
    int*      cursor = deg + Nn;                      // Nn
    float*    regp   = (float*)(cursor + Nn);         // 1 (+15 pad)
    unsigned* hcnt   = (unsigned*)(regp + 16);        // HS
    size_t zero_bytes = ((size_t)Nn + Nn + 16 + HS) * 4;
    // non-init region:
    unsigned* hkeys  = hcnt + HS;                     // HS (0xFF fill)
    int*      rowptr = (int*)(hkeys + HS);            // Nn+1
    int*      csr    = rowptr + Nn + 1;               // E
    float*    dinv   = (float*)(csr + E);             // Nn
    float*    H0     = dinv + Nn;                     // Nn*FH
    float*    AGG1   = H0 + (size_t)Nn * FH;          // Nn*FH
    float*    LG0    = AGG1 + (size_t)Nn * FH;        // Nn*FOUT

    hipMemsetAsync(d_ws, 0, zero_bytes, stream);
    hipMemsetAsync(hkeys, 0xFF, (size_t)HS * 4, stream);

    k_deg_hash<<<(E + 255) / 256, 256, 0, stream>>>(src, dst, E, Nn, deg, hkeys, hcnt);
    k_scan<<<1, 256, 0, stream>>>(deg, rowptr, dinv, Nn);
    k_fill<<<(E + 255) / 256, 256, 0, stream>>>(src, dst, E, rowptr, cursor, csr);

    // H0 = X @ W1
    gemm64<<<dim3((Nn + 63) / 64, (FH + 63) / 64), 256, 0, stream>>>(x, W1, H0, Nn, FH, FIN);
    // AGG1 = relu(gather(H0) + b1), wave per node
    k_agg1<<<(Nn * 64 + 255) / 256, 256, 0, stream>>>(rowptr, csr, dinv, H0, b1, AGG1, Nn);
    // LG0 = AGG1 @ W2
    gemm64<<<dim3((Nn + 63) / 64, (FOUT + 63) / 64), 256, 0, stream>>>(AGG1, W2, LG0, Nn, FOUT, FH);
    // reg lookup (must precede k_agg2_lsm which reads regp)
    k_reg<<<(E + 255) / 256, 256, 0, stream>>>(src, dst, E, Nn, hkeys, hcnt, regp);
    // out = log_softmax(gather(LG0) + b2), reg -> out[Nn*FOUT]
    k_agg2_lsm<<<(Nn * 64 + 255) / 256, 256, 0, stream>>>(rowptr, csr, dinv, LG0, b2, regp, out, Nn, FOUT);
}

// Round 3
// 335.132 us; speedup vs baseline: 1.3534x; 1.0246x over previous
//
#include <hip/hip_runtime.h>
#include <hip/hip_bf16.h>

// Problem: N=10000, E=320000, FIN=512, FH=128, FOUT=40 (derived from in_sizes).
// Pipeline: convert X->bf16, pack W1 into MFMA-fragment layout (hi+lo split)
//   -> deg+hash -> scan(rowptr,dinv) -> CSR fill
//   -> MFMA GEMM1 (bf16x2: X_bf @ W1_hi + X_bf @ W1_lo, fp32 accum)
//   -> gather-agg1(+bias+relu) -> fp32 GEMM2 -> reg lookup -> gather-agg2 + log_softmax.

#define HS (1u << 19)
#define HMASK (HS - 1u)
#define EMPTY_KEY 0xFFFFFFFFu

typedef __attribute__((ext_vector_type(8))) short short8;   // 8 x bf16 (4 VGPRs)
typedef __attribute__((ext_vector_type(4))) float float4v;  // MFMA C/D

__device__ __forceinline__ unsigned hash_u32(unsigned key) {
    unsigned h = key * 2654435761u;
    h ^= h >> 15;
    return h & HMASK;
}

__device__ __forceinline__ unsigned short f2bf(float f) {
    __hip_bfloat16 b = __float2bfloat16(f);
    return *reinterpret_cast<unsigned short*>(&b);
}
__device__ __forceinline__ float bf2f(unsigned short u) {
    __hip_bfloat16 b = *reinterpret_cast<__hip_bfloat16*>(&u);
    return __bfloat162float(b);
}

// ---- X fp32 -> bf16 (RNE), 4 elems/thread ----
__global__ void k_convx(const float* __restrict__ x, unsigned short* __restrict__ xh, int total4) {
    int i = blockIdx.x * blockDim.x + threadIdx.x;
    if (i >= total4) return;
    float4 v = ((const float4*)x)[i];
    ushort4 h;
    h.x = f2bf(v.x); h.y = f2bf(v.y); h.z = f2bf(v.z); h.w = f2bf(v.w);
    ((ushort4*)xh)[i] = h;
}

// ---- pack W1[K][N] into MFMA B-fragment order, hi + lo residual ----
// layout: [(kb*NF + f)*64 + lane]*8 bf16, where lane's j-th element is
// W[kb*32 + (lane>>4)*8 + j][f*16 + (lane&15)]
__global__ void k_packw(const float* __restrict__ W, unsigned short* __restrict__ Bh,
                        unsigned short* __restrict__ Bl, int KB, int NF, int Ndim) {
    int t = blockIdx.x * blockDim.x + threadIdx.x;
    if (t >= KB * NF * 64) return;
    int lane = t & 63;
    int f = (t >> 6) % NF;
    int kb = (t >> 6) / NF;
    int kbase = kb * 32 + (lane >> 4) * 8;
    int n = f * 16 + (lane & 15);
    ushort4 h0, h1, l0, l1;
    unsigned short hj[8], lj[8];
#pragma unroll
    for (int j = 0; j < 8; j++) {
        float v = W[(size_t)(kbase + j) * Ndim + n];
        unsigned short hb = f2bf(v);
        hj[j] = hb;
        lj[j] = f2bf(v - bf2f(hb));
    }
    h0 = {hj[0], hj[1], hj[2], hj[3]}; h1 = {hj[4], hj[5], hj[6], hj[7]};
    l0 = {lj[0], lj[1], lj[2], lj[3]}; l1 = {lj[4], lj[5], lj[6], lj[7]};
    ((ushort4*)Bh)[t * 2] = h0; ((ushort4*)Bh)[t * 2 + 1] = h1;
    ((ushort4*)Bl)[t * 2] = l0; ((ushort4*)Bl)[t * 2 + 1] = l1;
}

// ---- MFMA GEMM1: H0[M][N] = Xh[M][K] @ W1 (bf16x2), N=NF*16, K=KB*32 ----
template <int NF, int KB>
__global__ void k_mfma_gemm1(const unsigned short* __restrict__ Xh,
                             const unsigned short* __restrict__ Bh,
                             const unsigned short* __restrict__ Bl,
                             float* __restrict__ H0, int M) {
    const int K = KB * 32, N = NF * 16;
    int w = threadIdx.x >> 6, lane = threadIdx.x & 63;
    int m0 = blockIdx.x * 64 + w * 16;
    if (m0 >= M) return;
    float4v acc[NF] = {};
    const short8* A = (const short8*)(Xh + (size_t)(m0 + (lane & 15)) * K) + (lane >> 4);
    const short8* BH = ((const short8*)Bh) + lane;
    const short8* BL = ((const short8*)Bl) + lane;
    for (int kb = 0; kb < KB; kb++) {
        short8 a = A[kb * 4];
#pragma unroll
        for (int f = 0; f < NF; f++) {
            short8 bh = BH[(kb * NF + f) * 64];
            short8 bl = BL[(kb * NF + f) * 64];
            acc[f] = __builtin_amdgcn_mfma_f32_16x16x32_bf16(a, bh, acc[f], 0, 0, 0);
            acc[f] = __builtin_amdgcn_mfma_f32_16x16x32_bf16(a, bl, acc[f], 0, 0, 0);
        }
    }
    int row = (lane >> 4) * 4, col = lane & 15;
#pragma unroll
    for (int f = 0; f < NF; f++)
#pragma unroll
        for (int r = 0; r < 4; r++)
            H0[(size_t)(m0 + row + r) * N + f * 16 + col] = acc[f][r];
}

// ---- in-degree count + hash insert of edge keys (for reg) ----
__global__ void k_deg_hash(const int* __restrict__ src, const int* __restrict__ dst,
                           int E, int Nn, int* __restrict__ deg,
                           unsigned* __restrict__ hkeys, unsigned* __restrict__ hcnt) {
    int e = blockIdx.x * blockDim.x + threadIdx.x;
    if (e >= E) return;
    int s = src[e], d = dst[e];
    atomicAdd(&deg[d], 1);
    unsigned key = (unsigned)s * (unsigned)Nn + (unsigned)d;
    unsigned h = hash_u32(key);
    for (;;) {
        unsigned prev = atomicCAS(&hkeys[h], EMPTY_KEY, key);
        if (prev == EMPTY_KEY || prev == key) { atomicAdd(&hcnt[h], 1u); break; }
        h = (h + 1u) & HMASK;
    }
}

// ---- single-block exclusive scan of deg -> rowptr; also dinv = rsqrt(deg+1) ----
__global__ void k_scan(const int* __restrict__ deg, int* __restrict__ rowptr,
                       float* __restrict__ dinv, int Nn) {
    __shared__ int part[256];
    int t = threadIdx.x;
    int per = (Nn + 255) / 256;
    int beg = t * per, lim = min(beg + per, Nn);
    int sum = 0;
    for (int i = beg; i < lim; i++) sum += deg[i];
    part[t] = sum;
    __syncthreads();
    for (int off = 1; off < 256; off <<= 1) {
        int v = (t >= off) ? part[t - off] : 0;
        __syncthreads();
        part[t] += v;
        __syncthreads();
    }
    int run = (t > 0) ? part[t - 1] : 0;
    for (int i = beg; i < lim; i++) {
        rowptr[i] = run;
        run += deg[i];
        dinv[i] = rsqrtf((float)deg[i] + 1.0f);  // +1 self-loop
    }
    if (t == 255) rowptr[Nn] = run;
}

// ---- scatter edges into CSR buckets ----
__global__ void k_fill(const int* __restrict__ src, const int* __restrict__ dst, int E,
                       const int* __restrict__ rowptr, int* __restrict__ cursor,
                       int* __restrict__ csr) {
    int e = blockIdx.x * blockDim.x + threadIdx.x;
    if (e >= E) return;
    int d = dst[e];
    int pos = atomicAdd(&cursor[d], 1);
    csr[rowptr[d] + pos] = src[e];
}

// ---- fp32 tiled GEMM (used for GEMM2): C[M,N] = A[M,K] @ B[K,N] ----
__global__ void gemm64(const float* __restrict__ A, const float* __restrict__ B,
                       float* __restrict__ C, int M, int N, int K) {
    __shared__ float As[16][64];
    __shared__ float Bs[16][64];
    int row0 = blockIdx.x * 64, col0 = blockIdx.y * 64;
    int t = threadIdx.x;
    int tx = t & 15, ty = t >> 4;
    float acc[4][4] = {};
    for (int k0 = 0; k0 < K; k0 += 16) {
#pragma unroll
        for (int i = 0; i < 4; i++) {
            int idx = t + i * 256;
            int m = idx >> 4, kk = idx & 15;
            float va = 0.f;
            if (row0 + m < M) va = A[(size_t)(row0 + m) * K + k0 + kk];
            As[kk][m] = va;
            int k2 = idx >> 6, n2 = idx & 63;
            float vb = 0.f;
            if (col0 + n2 < N) vb = B[(size_t)(k0 + k2) * N + col0 + n2];
            Bs[k2][n2] = vb;
        }
        __syncthreads();
#pragma unroll
        for (int kk = 0; kk < 16; kk++) {
            float a[4], b[4];
#pragma unroll
            for (int i = 0; i < 4; i++) a[i] = As[kk][ty * 4 + i];
#pragma unroll
            for (int j = 0; j < 4; j++) b[j] = Bs[kk][tx * 4 + j];
#pragma unroll
            for (int i = 0; i < 4; i++)
#pragma unroll
                for (int j = 0; j < 4; j++) acc[i][j] += a[i] * b[j];
        }
        __syncthreads();
    }
#pragma unroll
    for (int i = 0; i < 4; i++) {
        int m = row0 + ty * 4 + i;
        if (m >= M) continue;
#pragma unroll
        for (int j = 0; j < 4; j++) {
            int n = col0 + tx * 4 + j;
            if (n < N) C[(size_t)m * N + n] = acc[i][j];
        }
    }
}

// ---- layer-1 gather aggregation, wave per dst node, FH=128 (float2/lane), fused bias+relu ----
__global__ void k_agg1(const int* __restrict__ rowptr, const int* __restrict__ csr,
                       const float* __restrict__ dinv, const float* __restrict__ H,
                       const float* __restrict__ b1, float* __restrict__ out, int Nn) {
    int wid = (blockIdx.x * blockDim.x + threadIdx.x) >> 6;
    int lane = threadIdx.x & 63;
    if (wid >= Nn) return;
    float dd = dinv[wid];
    const float2* H2 = (const float2*)H;
    float2 h = H2[(size_t)wid * 64 + lane];
    float sw = dd * dd;
    float accx = h.x * sw, accy = h.y * sw;   // self-loop
    int beg = rowptr[wid], end = rowptr[wid + 1];
    int j = beg;
    for (; j + 1 < end; j += 2) {
        int s0 = csr[j], s1 = csr[j + 1];
        float w0 = dinv[s0] * dd, w1 = dinv[s1] * dd;
        float2 a = H2[(size_t)s0 * 64 + lane];
        float2 b = H2[(size_t)s1 * 64 + lane];
        accx += w0 * a.x + w1 * b.x;
        accy += w0 * a.y + w1 * b.y;
    }
    if (j < end) {
        int s0 = csr[j];
        float w0 = dinv[s0] * dd;
        float2 a = H2[(size_t)s0 * 64 + lane];
        accx += w0 * a.x;
        accy += w0 * a.y;
    }
    float2 bb = ((const float2*)b1)[lane];
    float vx = accx + bb.x, vy = accy + bb.y;
    float2 o;
    o.x = vx > 0.f ? vx : 0.f;
    o.y = vy > 0.f ? vy : 0.f;
    ((float2*)out)[(size_t)wid * 64 + lane] = o;
}

// ---- reg = sum over edge instances (s,d) of count(d,s) ----
__global__ void k_reg(const int* __restrict__ src, const int* __restrict__ dst,
                      int E, int Nn, const unsigned* __restrict__ hkeys,
                      const unsigned* __restrict__ hcnt, float* __restrict__ regp) {
    int e = blockIdx.x * blockDim.x + threadIdx.x;
    if (e >= E) return;
    int s = src[e], d = dst[e];
    unsigned key = (unsigned)d * (unsigned)Nn + (unsigned)s;
    unsigned h = hash_u32(key);
    unsigned c = 0;
    for (;;) {
        unsigned k = hkeys[h];
        if (k == EMPTY_KEY) break;
        if (k == key) { c = hcnt[h]; break; }
        h = (h + 1u) & HMASK;
    }
    if (c) atomicAdd(regp, (float)c);
}

// ---- layer-2 gather aggregation + bias + log_softmax, wave per dst node ----
__global__ void k_agg2_lsm(const int* __restrict__ rowptr, const int* __restrict__ csr,
                           const float* __restrict__ dinv, const float* __restrict__ LG,
                           const float* __restrict__ b2, const float* __restrict__ regp,
                           float* __restrict__ out, int Nn, int F) {
    int wid = (blockIdx.x * blockDim.x + threadIdx.x) >> 6;
    int lane = threadIdx.x & 63;
    if (wid >= Nn) return;
    float dd = dinv[wid];
    bool act = lane < F;
    float acc = act ? LG[(size_t)wid * F + lane] * dd * dd : 0.f;  // self-loop
    int beg = rowptr[wid], end = rowptr[wid + 1];
    int j = beg;
    for (; j + 1 < end; j += 2) {
        int s0 = csr[j], s1 = csr[j + 1];
        float w0 = dinv[s0] * dd, w1 = dinv[s1] * dd;
        float a0 = act ? LG[(size_t)s0 * F + lane] : 0.f;
        float a1 = act ? LG[(size_t)s1 * F + lane] : 0.f;
        acc += w0 * a0 + w1 * a1;
    }
    if (j < end) {
        int s0 = csr[j];
        float w0 = dinv[s0] * dd;
        float a0 = act ? LG[(size_t)s0 * F + lane] : 0.f;
        acc += w0 * a0;
    }
    float v = act ? acc + b2[lane] : -1e30f;
    float m = v;
#pragma unroll
    for (int off = 32; off; off >>= 1) m = fmaxf(m, __shfl_xor(m, off, 64));
    float ex = act ? expf(v - m) : 0.f;
    float ssum = ex;
#pragma unroll
    for (int off = 32; off; off >>= 1) ssum += __shfl_xor(ssum, off, 64);
    if (act) out[(size_t)wid * F + lane] = v - m - logf(ssum);
    if (wid == 0 && lane == 0) out[(size_t)Nn * F] = regp[0];
}

extern "C" void kernel_launch(void* const* d_in, const int* in_sizes, int n_in,
                              void* d_out, int out_size, void* d_ws, size_t ws_size,
                              hipStream_t stream) {
    const float* x  = (const float*)d_in[0];
    const int*   ei = (const int*)d_in[1];
    const float* W1 = (const float*)d_in[2];
    const float* b1 = (const float*)d_in[3];
    const float* W2 = (const float*)d_in[4];
    const float* b2 = (const float*)d_in[5];
    float* out = (float*)d_out;

    const int FH   = in_sizes[3];            // 128
    const int FOUT = in_sizes[5];            // 40
    const int FIN  = in_sizes[2] / FH;       // 512
    const int Nn   = in_sizes[0] / FIN;      // 10000
    const int E    = in_sizes[1] / 2;        // 320000
    const int* src = ei;
    const int* dst = ei + E;
    const int KB = FIN / 32, NF = FH / 16;   // 16, 8

    // ---- workspace layout (float units) ----
    // zero-init region (contiguous): deg, cursor, regp(+pad), hcnt
    int*      deg    = (int*)d_ws;                        // Nn
    int*      cursor = deg + Nn;                          // Nn
    float*    regp   = (float*)(cursor + Nn);             // 1 (+15 pad)
    unsigned* hcnt   = (unsigned*)(regp + 16);            // HS
    size_t zero_bytes = ((size_t)Nn + Nn + 16 + HS) * 4;
    // non-init region:
    unsigned* hkeys  = hcnt + HS;                         // HS (0xFF fill)
    int*      rowptr = (int*)(hkeys + HS);                // Nn+1
    int*      csr    = rowptr + Nn + 1;                   // E
    float*    dinv   = (float*)(csr + E);                 // Nn
    float*    H0     = dinv + Nn;                         // Nn*FH
    float*    AGG1   = H0 + (size_t)Nn * FH;              // Nn*FH
    float*    LG0    = AGG1 + (size_t)Nn * FH;            // Nn*FOUT
    unsigned short* Xh = (unsigned short*)(LG0 + (size_t)Nn * FOUT);  // Nn*FIN bf16
    unsigned short* Bh = Xh + (size_t)Nn * FIN;           // KB*NF*64*8 bf16
    unsigned short* Bl = Bh + (size_t)KB * NF * 64 * 8;   // same

    hipMemsetAsync(d_ws, 0, zero_bytes, stream);
    hipMemsetAsync(hkeys, 0xFF, (size_t)HS * 4, stream);

    // convert + pack (independent of graph prep; stream-ordered anyway)
    k_convx<<<(Nn * FIN / 4 + 255) / 256, 256, 0, stream>>>(x, Xh, Nn * FIN / 4);
    k_packw<<<(KB * NF * 64 + 255) / 256, 256, 0, stream>>>(W1, Bh, Bl, KB, NF, FH);

    k_deg_hash<<<(E + 255) / 256, 256, 0, stream>>>(src, dst, E, Nn, deg, hkeys, hcnt);
    k_scan<<<1, 256, 0, stream>>>(deg, rowptr, dinv, Nn);
    k_fill<<<(E + 255) / 256, 256, 0, stream>>>(src, dst, E, rowptr, cursor, csr);

    // H0 = X @ W1 via MFMA bf16x2
    k_mfma_gemm1<8, 16><<<(Nn + 63) / 64, 256, 0, stream>>>(Xh, Bh, Bl, H0, Nn);
    // AGG1 = relu(gather(H0) + b1), wave per node
    k_agg1<<<(Nn * 64 + 255) / 256, 256, 0, stream>>>(rowptr, csr, dinv, H0, b1, AGG1, Nn);
    // LG0 = AGG1 @ W2 (fp32 vector GEMM)
    gemm64<<<dim3((Nn + 63) / 64, (FOUT + 63) / 64), 256, 0, stream>>>(AGG1, W2, LG0, Nn, FOUT, FH);
    // reg lookup (must precede k_agg2_lsm which reads regp)
    k_reg<<<(E + 255) / 256, 256, 0, stream>>>(src, dst, E, Nn, hkeys, hcnt, regp);
    // out = log_softmax(gather(LG0) + b2), reg -> out[Nn*FOUT]
    k_agg2_lsm<<<(Nn * 64 + 255) / 256, 256, 0, stream>>>(rowptr, csr, dinv, LG0, b2, regp, out, Nn, FOUT);
}

// Round 4
// 287.330 us; speedup vs baseline: 1.5785x; 1.1664x over previous
//
#include <hip/hip_runtime.h>
#include <hip/hip_bf16.h>

// Problem: N=10000, E=320000, FIN=512, FH=128, FOUT=40 (derived from in_sizes).
// Pipeline: convert X->bf16 + pack W1 (hi+lo bf16 split)
//   -> deg -> scan(rowptr,dinv) -> CSR fill
//   -> MFMA GEMM1 (bf16x2, fp32 accum) -> gather-agg1(+bias+relu)
//   -> fp32 GEMM2 -> reg via CSR scan -> gather-agg2 + log_softmax.
// reg identity: reg = sum_{(s,d) in E} cnt(d,s), and cnt(d,s) = #occurrences of d
// in the src-list (CSR by dst) of node s. No hash table needed.

typedef __attribute__((ext_vector_type(8))) short short8;   // 8 x bf16 (4 VGPRs)
typedef __attribute__((ext_vector_type(4))) float float4v;  // MFMA C/D

__device__ __forceinline__ unsigned short f2bf(float f) {
    __hip_bfloat16 b = __float2bfloat16(f);
    return *reinterpret_cast<unsigned short*>(&b);
}
__device__ __forceinline__ float bf2f(unsigned short u) {
    __hip_bfloat16 b = *reinterpret_cast<__hip_bfloat16*>(&u);
    return __bfloat162float(b);
}

// ---- X fp32 -> bf16 (RNE), 4 elems/thread ----
__global__ void k_convx(const float* __restrict__ x, unsigned short* __restrict__ xh, int total4) {
    int i = blockIdx.x * blockDim.x + threadIdx.x;
    if (i >= total4) return;
    float4 v = ((const float4*)x)[i];
    ushort4 h;
    h.x = f2bf(v.x); h.y = f2bf(v.y); h.z = f2bf(v.z); h.w = f2bf(v.w);
    ((ushort4*)xh)[i] = h;
}

// ---- pack W1[K][N] into MFMA B-fragment order, hi + lo residual ----
__global__ void k_packw(const float* __restrict__ W, unsigned short* __restrict__ Bh,
                        unsigned short* __restrict__ Bl, int KB, int NF, int Ndim) {
    int t = blockIdx.x * blockDim.x + threadIdx.x;
    if (t >= KB * NF * 64) return;
    int lane = t & 63;
    int f = (t >> 6) % NF;
    int kb = (t >> 6) / NF;
    int kbase = kb * 32 + (lane >> 4) * 8;
    int n = f * 16 + (lane & 15);
    unsigned short hj[8], lj[8];
#pragma unroll
    for (int j = 0; j < 8; j++) {
        float v = W[(size_t)(kbase + j) * Ndim + n];
        unsigned short hb = f2bf(v);
        hj[j] = hb;
        lj[j] = f2bf(v - bf2f(hb));
    }
    ushort4 h0 = {hj[0], hj[1], hj[2], hj[3]}, h1 = {hj[4], hj[5], hj[6], hj[7]};
    ushort4 l0 = {lj[0], lj[1], lj[2], lj[3]}, l1 = {lj[4], lj[5], lj[6], lj[7]};
    ((ushort4*)Bh)[t * 2] = h0; ((ushort4*)Bh)[t * 2 + 1] = h1;
    ((ushort4*)Bl)[t * 2] = l0; ((ushort4*)Bl)[t * 2 + 1] = l1;
}

// ---- MFMA GEMM1: H0[M][N] = Xh[M][K] @ W1 (bf16x2), N=NF*16, K=KB*32 ----
template <int NF, int KB>
__global__ void k_mfma_gemm1(const unsigned short* __restrict__ Xh,
                             const unsigned short* __restrict__ Bh,
                             const unsigned short* __restrict__ Bl,
                             float* __restrict__ H0, int M) {
    const int K = KB * 32, N = NF * 16;
    int w = threadIdx.x >> 6, lane = threadIdx.x & 63;
    int m0 = blockIdx.x * 64 + w * 16;
    if (m0 >= M) return;
    float4v acc[NF] = {};
    const short8* A = (const short8*)(Xh + (size_t)(m0 + (lane & 15)) * K) + (lane >> 4);
    const short8* BH = ((const short8*)Bh) + lane;
    const short8* BL = ((const short8*)Bl) + lane;
    for (int kb = 0; kb < KB; kb++) {
        short8 a = A[kb * 4];
#pragma unroll
        for (int f = 0; f < NF; f++) {
            short8 bh = BH[(kb * NF + f) * 64];
            short8 bl = BL[(kb * NF + f) * 64];
            acc[f] = __builtin_amdgcn_mfma_f32_16x16x32_bf16(a, bh, acc[f], 0, 0, 0);
            acc[f] = __builtin_amdgcn_mfma_f32_16x16x32_bf16(a, bl, acc[f], 0, 0, 0);
        }
    }
    int row = (lane >> 4) * 4, col = lane & 15;
#pragma unroll
    for (int f = 0; f < NF; f++)
#pragma unroll
        for (int r = 0; r < 4; r++)
            H0[(size_t)(m0 + row + r) * N + f * 16 + col] = acc[f][r];
}

// ---- in-degree count ----
__global__ void k_deg(const int* __restrict__ dst, int E, int* __restrict__ deg) {
    int e = blockIdx.x * blockDim.x + threadIdx.x;
    if (e >= E) return;
    atomicAdd(&deg[dst[e]], 1);
}

// ---- single-block exclusive scan of deg -> rowptr; also dinv = rsqrt(deg+1) ----
__global__ void k_scan(const int* __restrict__ deg, int* __restrict__ rowptr,
                       float* __restrict__ dinv, int Nn) {
    __shared__ int part[256];
    int t = threadIdx.x;
    int per = (Nn + 255) / 256;
    int beg = t * per, lim = min(beg + per, Nn);
    int sum = 0;
    for (int i = beg; i < lim; i++) sum += deg[i];
    part[t] = sum;
    __syncthreads();
    for (int off = 1; off < 256; off <<= 1) {
        int v = (t >= off) ? part[t - off] : 0;
        __syncthreads();
        part[t] += v;
        __syncthreads();
    }
    int run = (t > 0) ? part[t - 1] : 0;
    for (int i = beg; i < lim; i++) {
        rowptr[i] = run;
        run += deg[i];
        dinv[i] = rsqrtf((float)deg[i] + 1.0f);  // +1 self-loop
    }
    if (t == 255) rowptr[Nn] = run;
}

// ---- scatter edges into CSR buckets ----
__global__ void k_fill(const int* __restrict__ src, const int* __restrict__ dst, int E,
                       const int* __restrict__ rowptr, int* __restrict__ cursor,
                       int* __restrict__ csr) {
    int e = blockIdx.x * blockDim.x + threadIdx.x;
    if (e >= E) return;
    int d = dst[e];
    int pos = atomicAdd(&cursor[d], 1);
    csr[rowptr[d] + pos] = src[e];
}

// ---- reg: per edge (s,d), count occurrences of d in s's src-list; wave-reduce ----
__global__ void k_reg_csr(const int* __restrict__ src, const int* __restrict__ dst, int E,
                          const int* __restrict__ rowptr, const int* __restrict__ csr,
                          float* __restrict__ regp) {
    int e = blockIdx.x * blockDim.x + threadIdx.x;
    int c = 0;
    if (e < E) {
        int s = src[e], d = dst[e];
        int beg = rowptr[s], end = rowptr[s + 1];
        for (int j = beg; j < end; j++) c += (csr[j] == d) ? 1 : 0;
    }
#pragma unroll
    for (int off = 32; off; off >>= 1) c += __shfl_xor(c, off, 64);
    if ((threadIdx.x & 63) == 0 && c) atomicAdd(regp, (float)c);
}

// ---- fp32 tiled GEMM (used for GEMM2): C[M,N] = A[M,K] @ B[K,N] ----
__global__ void gemm64(const float* __restrict__ A, const float* __restrict__ B,
                       float* __restrict__ C, int M, int N, int K) {
    __shared__ float As[16][64];
    __shared__ float Bs[16][64];
    int row0 = blockIdx.x * 64, col0 = blockIdx.y * 64;
    int t = threadIdx.x;
    int tx = t & 15, ty = t >> 4;
    float acc[4][4] = {};
    for (int k0 = 0; k0 < K; k0 += 16) {
#pragma unroll
        for (int i = 0; i < 4; i++) {
            int idx = t + i * 256;
            int m = idx >> 4, kk = idx & 15;
            float va = 0.f;
            if (row0 + m < M) va = A[(size_t)(row0 + m) * K + k0 + kk];
            As[kk][m] = va;
            int k2 = idx >> 6, n2 = idx & 63;
            float vb = 0.f;
            if (col0 + n2 < N) vb = B[(size_t)(k0 + k2) * N + col0 + n2];
            Bs[k2][n2] = vb;
        }
        __syncthreads();
#pragma unroll
        for (int kk = 0; kk < 16; kk++) {
            float a[4], b[4];
#pragma unroll
            for (int i = 0; i < 4; i++) a[i] = As[kk][ty * 4 + i];
#pragma unroll
            for (int j = 0; j < 4; j++) b[j] = Bs[kk][tx * 4 + j];
#pragma unroll
            for (int i = 0; i < 4; i++)
#pragma unroll
                for (int j = 0; j < 4; j++) acc[i][j] += a[i] * b[j];
        }
        __syncthreads();
    }
#pragma unroll
    for (int i = 0; i < 4; i++) {
        int m = row0 + ty * 4 + i;
        if (m >= M) continue;
#pragma unroll
        for (int j = 0; j < 4; j++) {
            int n = col0 + tx * 4 + j;
            if (n < N) C[(size_t)m * N + n] = acc[i][j];
        }
    }
}

// ---- layer-1 gather aggregation, wave per dst node, FH=128 (float2/lane), fused bias+relu ----
__global__ void k_agg1(const int* __restrict__ rowptr, const int* __restrict__ csr,
                       const float* __restrict__ dinv, const float* __restrict__ H,
                       const float* __restrict__ b1, float* __restrict__ out, int Nn) {
    int wid = (blockIdx.x * blockDim.x + threadIdx.x) >> 6;
    int lane = threadIdx.x & 63;
    if (wid >= Nn) return;
    float dd = dinv[wid];
    const float2* H2 = (const float2*)H;
    float2 h = H2[(size_t)wid * 64 + lane];
    float sw = dd * dd;
    float accx = h.x * sw, accy = h.y * sw;   // self-loop
    int beg = rowptr[wid], end = rowptr[wid + 1];
    int j = beg;
    for (; j + 1 < end; j += 2) {
        int s0 = csr[j], s1 = csr[j + 1];
        float w0 = dinv[s0] * dd, w1 = dinv[s1] * dd;
        float2 a = H2[(size_t)s0 * 64 + lane];
        float2 b = H2[(size_t)s1 * 64 + lane];
        accx += w0 * a.x + w1 * b.x;
        accy += w0 * a.y + w1 * b.y;
    }
    if (j < end) {
        int s0 = csr[j];
        float w0 = dinv[s0] * dd;
        float2 a = H2[(size_t)s0 * 64 + lane];
        accx += w0 * a.x;
        accy += w0 * a.y;
    }
    float2 bb = ((const float2*)b1)[lane];
    float vx = accx + bb.x, vy = accy + bb.y;
    float2 o;
    o.x = vx > 0.f ? vx : 0.f;
    o.y = vy > 0.f ? vy : 0.f;
    ((float2*)out)[(size_t)wid * 64 + lane] = o;
}

// ---- layer-2 gather aggregation + bias + log_softmax, wave per dst node ----
__global__ void k_agg2_lsm(const int* __restrict__ rowptr, const int* __restrict__ csr,
                           const float* __restrict__ dinv, const float* __restrict__ LG,
                           const float* __restrict__ b2, const float* __restrict__ regp,
                           float* __restrict__ out, int Nn, int F) {
    int wid = (blockIdx.x * blockDim.x + threadIdx.x) >> 6;
    int lane = threadIdx.x & 63;
    if (wid >= Nn) return;
    float dd = dinv[wid];
    bool act = lane < F;
    float acc = act ? LG[(size_t)wid * F + lane] * dd * dd : 0.f;  // self-loop
    int beg = rowptr[wid], end = rowptr[wid + 1];
    int j = beg;
    for (; j + 1 < end; j += 2) {
        int s0 = csr[j], s1 = csr[j + 1];
        float w0 = dinv[s0] * dd, w1 = dinv[s1] * dd;
        float a0 = act ? LG[(size_t)s0 * F + lane] : 0.f;
        float a1 = act ? LG[(size_t)s1 * F + lane] : 0.f;
        acc += w0 * a0 + w1 * a1;
    }
    if (j < end) {
        int s0 = csr[j];
        float w0 = dinv[s0] * dd;
        float a0 = act ? LG[(size_t)s0 * F + lane] : 0.f;
        acc += w0 * a0;
    }
    float v = act ? acc + b2[lane] : -1e30f;
    float m = v;
#pragma unroll
    for (int off = 32; off; off >>= 1) m = fmaxf(m, __shfl_xor(m, off, 64));
    float ex = act ? expf(v - m) : 0.f;
    float ssum = ex;
#pragma unroll
    for (int off = 32; off; off >>= 1) ssum += __shfl_xor(ssum, off, 64);
    if (act) out[(size_t)wid * F + lane] = v - m - logf(ssum);
    if (wid == 0 && lane == 0) out[(size_t)Nn * F] = regp[0];
}

extern "C" void kernel_launch(void* const* d_in, const int* in_sizes, int n_in,
                              void* d_out, int out_size, void* d_ws, size_t ws_size,
                              hipStream_t stream) {
    const float* x  = (const float*)d_in[0];
    const int*   ei = (const int*)d_in[1];
    const float* W1 = (const float*)d_in[2];
    const float* b1 = (const float*)d_in[3];
    const float* W2 = (const float*)d_in[4];
    const float* b2 = (const float*)d_in[5];
    float* out = (float*)d_out;

    const int FH   = in_sizes[3];            // 128
    const int FOUT = in_sizes[5];            // 40
    const int FIN  = in_sizes[2] / FH;       // 512
    const int Nn   = in_sizes[0] / FIN;      // 10000
    const int E    = in_sizes[1] / 2;        // 320000
    const int* src = ei;
    const int* dst = ei + E;
    const int KB = FIN / 32, NF = FH / 16;   // 16, 8

    // ---- workspace layout ----
    // zero-init region (contiguous): deg, cursor, regp(+pad)
    int*      deg    = (int*)d_ws;                        // Nn
    int*      cursor = deg + Nn;                          // Nn
    float*    regp   = (float*)(cursor + Nn);             // 1 (+15 pad)
    size_t zero_bytes = ((size_t)Nn + Nn + 16) * 4;
    // non-init region:
    int*      rowptr = (int*)(regp + 16);                 // Nn+1
    int*      csr    = rowptr + Nn + 1;                   // E
    float*    dinv   = (float*)(csr + E);                 // Nn
    float*    H0     = dinv + Nn;                         // Nn*FH
    float*    AGG1   = H0 + (size_t)Nn * FH;              // Nn*FH
    float*    LG0    = AGG1 + (size_t)Nn * FH;            // Nn*FOUT
    unsigned short* Xh = (unsigned short*)(LG0 + (size_t)Nn * FOUT);  // Nn*FIN bf16
    unsigned short* Bh = Xh + (size_t)Nn * FIN;           // KB*NF*64*8 bf16
    unsigned short* Bl = Bh + (size_t)KB * NF * 64 * 8;   // same

    hipMemsetAsync(d_ws, 0, zero_bytes, stream);

    // convert + pack (independent of graph prep; stream-ordered anyway)
    k_convx<<<(Nn * FIN / 4 + 255) / 256, 256, 0, stream>>>(x, Xh, Nn * FIN / 4);
    k_packw<<<(KB * NF * 64 + 255) / 256, 256, 0, stream>>>(W1, Bh, Bl, KB, NF, FH);

    k_deg<<<(E + 255) / 256, 256, 0, stream>>>(dst, E, deg);
    k_scan<<<1, 256, 0, stream>>>(deg, rowptr, dinv, Nn);
    k_fill<<<(E + 255) / 256, 256, 0, stream>>>(src, dst, E, rowptr, cursor, csr);

    // H0 = X @ W1 via MFMA bf16x2
    k_mfma_gemm1<8, 16><<<(Nn + 63) / 64, 256, 0, stream>>>(Xh, Bh, Bl, H0, Nn);
    // AGG1 = relu(gather(H0) + b1), wave per node
    k_agg1<<<(Nn * 64 + 255) / 256, 256, 0, stream>>>(rowptr, csr, dinv, H0, b1, AGG1, Nn);
    // LG0 = AGG1 @ W2 (fp32 vector GEMM)
    gemm64<<<dim3((Nn + 63) / 64, (FOUT + 63) / 64), 256, 0, stream>>>(AGG1, W2, LG0, Nn, FOUT, FH);
    // reg via CSR scan (needs csr filled; must precede k_agg2_lsm which reads regp)
    k_reg_csr<<<(E + 255) / 256, 256, 0, stream>>>(src, dst, E, rowptr, csr, regp);
    // out = log_softmax(gather(LG0) + b2), reg -> out[Nn*FOUT]
    k_agg2_lsm<<<(Nn * 64 + 255) / 256, 256, 0, stream>>>(rowptr, csr, dinv, LG0, b2, regp, out, Nn, FOUT);
}